// Round 1
// baseline (141.206 us; speedup 1.0000x reference)
//
#include <hip/hip_runtime.h>
#include <hip/hip_bf16.h>

// NCF fused forward. Block = 64 (user,item) pairs, 256 threads (4 waves).
// Phases: gather->LDS, GEMM1(128x128), GEMM2(128x64), GEMM3(64x32), final dot+sigmoid.
// Weights pre-transposed to bf16 [out][in] in d_ws by ncf_prep.

typedef __attribute__((ext_vector_type(8))) short bf16x8;
typedef __attribute__((ext_vector_type(4))) float f32x4;

__device__ __forceinline__ short f2bf(float x){
  unsigned u = __float_as_uint(x);
  u += 0x7fffu + ((u >> 16) & 1u);
  return (short)(u >> 16);
}
__device__ __forceinline__ float bf2f(short s){
  return __uint_as_float(((unsigned)(unsigned short)s) << 16);
}

// ---- prep: W1[128,128],W2[128,64],W3[64,32] (stored [in][out]) -> bf16 [out][in] in ws ----
__global__ __launch_bounds__(256) void ncf_prep(
    const float* __restrict__ W1, const float* __restrict__ W2,
    const float* __restrict__ W3, short* __restrict__ ws)
{
  int i = blockIdx.x * 256 + threadIdx.x;
  if (i < 128*128){
    int j = i >> 7, k = i & 127;                 // W1T[j][k] = W1[k][j]
    ws[i] = f2bf(W1[k*128 + j]);
  } else if (i < 128*128 + 64*128){
    int t = i - 128*128; int j = t >> 7, k = t & 127;  // W2T[j][k] = W2[k][j]
    ws[i] = f2bf(W2[k*64 + j]);
  } else if (i < 128*128 + 64*128 + 32*64){
    int t = i - (128*128 + 64*128); int j = t >> 6, k = t & 63; // W3T[j][k] = W3[k][j]
    ws[i] = f2bf(W3[k*32 + j]);
  }
}

__global__ __launch_bounds__(256) void ncf_main(
    const int* __restrict__ user, const int* __restrict__ item,
    const float* __restrict__ Wu_gmf, const float* __restrict__ bu_gmf,
    const float* __restrict__ Wu_mlp, const float* __restrict__ bu_mlp,
    const float* __restrict__ Wi_gmf, const float* __restrict__ bi_gmf,
    const float* __restrict__ Wi_mlp, const float* __restrict__ bi_mlp,
    const short* __restrict__ W1T, const float* __restrict__ b1,
    const short* __restrict__ W2T, const float* __restrict__ b2,
    const short* __restrict__ W3T, const float* __restrict__ b3,
    const float* __restrict__ Wp, const float* __restrict__ bp,
    float* __restrict__ out, int N, int total)
{
  // LDS: +8 short pad on 128-wide rows keeps ds_read_b128 conflicts ~2-way.
  __shared__ __align__(16) short s_inter[64][136];  // inter (bf16); reused as h2 (cols 0..63)
  __shared__ __align__(16) short s_h1[64][136];     // h1 (bf16)
  __shared__ __align__(16) short s_gmf[64][72];     // gmf (bf16)
  __shared__ __align__(16) float s_h3[64][36];      // h3 (f32)

  const int tid = threadIdx.x;
  const int p0  = blockIdx.x * 64;

  // ---------- gather ----------
  {
    int r = tid >> 2, q = tid & 3;
    int p = p0 + r; if (p >= total) p = total - 1;
    int b = p / N;
    long ub = (long)user[b] * 64;
    long ib = (long)item[p] * 64;
    int e0 = q * 16;
    const float4* um  = (const float4*)(Wu_mlp + ub + e0);
    const float4* im  = (const float4*)(Wi_mlp + ib + e0);
    const float4* ug  = (const float4*)(Wu_gmf + ub + e0);
    const float4* ig  = (const float4*)(Wi_gmf + ib + e0);
    const float4* bum = (const float4*)(bu_mlp + e0);
    const float4* bim = (const float4*)(bi_mlp + e0);
    const float4* bug = (const float4*)(bu_gmf + e0);
    const float4* big = (const float4*)(bi_gmf + e0);
    #pragma unroll
    for (int j = 0; j < 4; j++){
      float4 a  = um[j],  ab = bum[j];
      float4 c  = im[j],  cb = bim[j];
      float4 g1 = ug[j],  g1b = bug[j];
      float4 g2 = ig[j],  g2b = big[j];
      float va[4] = {a.x+ab.x, a.y+ab.y, a.z+ab.z, a.w+ab.w};
      float vc[4] = {c.x+cb.x, c.y+cb.y, c.z+cb.z, c.w+cb.w};
      float vu[4] = {g1.x+g1b.x, g1.y+g1b.y, g1.z+g1b.z, g1.w+g1b.w};
      float vi[4] = {g2.x+g2b.x, g2.y+g2b.y, g2.z+g2b.z, g2.w+g2b.w};
      #pragma unroll
      for (int ii = 0; ii < 4; ii++){
        int e = e0 + 4*j + ii;
        s_inter[r][e]      = f2bf(va[ii]);
        s_inter[r][64 + e] = f2bf(vc[ii]);
        s_gmf[r][e]        = f2bf(vu[ii] * vi[ii]);
      }
    }
  }
  __syncthreads();

  const int w  = tid >> 6, l = tid & 63;
  const int lr = l & 15,  lg = l >> 4;

  // ---------- GEMM1: h1[64x128] = relu(inter[64x128] @ W1[128x128] + b1) ----------
  f32x4 acc[4][2];
  #pragma unroll
  for (int mt = 0; mt < 4; mt++)
    #pragma unroll
    for (int nt = 0; nt < 2; nt++)
      acc[mt][nt] = (f32x4){0.f, 0.f, 0.f, 0.f};
  #pragma unroll
  for (int ks = 0; ks < 4; ks++){
    bf16x8 af[4];
    #pragma unroll
    for (int mt = 0; mt < 4; mt++)
      af[mt] = *(const bf16x8*)&s_inter[mt*16 + lr][ks*32 + lg*8];
    #pragma unroll
    for (int nt = 0; nt < 2; nt++){
      bf16x8 bfg = *(const bf16x8*)&W1T[(w*32 + nt*16 + lr)*128 + ks*32 + lg*8];
      #pragma unroll
      for (int mt = 0; mt < 4; mt++)
        acc[mt][nt] = __builtin_amdgcn_mfma_f32_16x16x32_bf16(af[mt], bfg, acc[mt][nt], 0, 0, 0);
    }
  }
  #pragma unroll
  for (int nt = 0; nt < 2; nt++){
    int col = w*32 + nt*16 + lr;
    float bb = b1[col];
    #pragma unroll
    for (int mt = 0; mt < 4; mt++)
      #pragma unroll
      for (int rr = 0; rr < 4; rr++){
        int row = mt*16 + lg*4 + rr;
        float v = acc[mt][nt][rr] + bb;
        s_h1[row][col] = f2bf(v > 0.f ? v : 0.f);
      }
  }
  __syncthreads();

  // ---------- GEMM2: h2[64x64] = relu(h1 @ W2[128x64] + b2) -> s_inter cols 0..63 ----------
  f32x4 acc2[4];
  #pragma unroll
  for (int mt = 0; mt < 4; mt++) acc2[mt] = (f32x4){0.f, 0.f, 0.f, 0.f};
  #pragma unroll
  for (int ks = 0; ks < 4; ks++){
    bf16x8 bfg = *(const bf16x8*)&W2T[(w*16 + lr)*128 + ks*32 + lg*8];
    #pragma unroll
    for (int mt = 0; mt < 4; mt++){
      bf16x8 a = *(const bf16x8*)&s_h1[mt*16 + lr][ks*32 + lg*8];
      acc2[mt] = __builtin_amdgcn_mfma_f32_16x16x32_bf16(a, bfg, acc2[mt], 0, 0, 0);
    }
  }
  {
    int col = w*16 + lr;          // 0..63
    float bb = b2[col];
    #pragma unroll
    for (int mt = 0; mt < 4; mt++)
      #pragma unroll
      for (int rr = 0; rr < 4; rr++){
        int row = mt*16 + lg*4 + rr;
        float v = acc2[mt][rr] + bb;
        s_inter[row][col] = f2bf(v > 0.f ? v : 0.f);   // GEMM1 readers all past barrier
      }
  }
  __syncthreads();

  // ---------- GEMM3: h3[64x32] = relu(h2[64x64] @ W3[64x32] + b3) (waves 0,1) ----------
  if (w < 2){
    f32x4 acc3[4];
    #pragma unroll
    for (int mt = 0; mt < 4; mt++) acc3[mt] = (f32x4){0.f, 0.f, 0.f, 0.f};
    #pragma unroll
    for (int ks = 0; ks < 2; ks++){
      bf16x8 bfg = *(const bf16x8*)&W3T[(w*16 + lr)*64 + ks*32 + lg*8];
      #pragma unroll
      for (int mt = 0; mt < 4; mt++){
        bf16x8 a = *(const bf16x8*)&s_inter[mt*16 + lr][ks*32 + lg*8];
        acc3[mt] = __builtin_amdgcn_mfma_f32_16x16x32_bf16(a, bfg, acc3[mt], 0, 0, 0);
      }
    }
    int col = w*16 + lr;          // 0..31
    float bb = b3[col];
    #pragma unroll
    for (int mt = 0; mt < 4; mt++)
      #pragma unroll
      for (int rr = 0; rr < 4; rr++){
        int row = mt*16 + lg*4 + rr;
        float v = acc3[mt][rr] + bb;
        s_h3[row][col] = v > 0.f ? v : 0.f;
      }
  }
  __syncthreads();

  // ---------- final: out = sigmoid([gmf(64), h3(32)] . Wp + bp) ----------
  {
    int row = w*16 + (l >> 2);
    int q   = l & 3;
    float sum = 0.f;
    #pragma unroll
    for (int i = 0; i < 24; i++){
      int c = q*24 + i;
      float v = (c < 64) ? bf2f(s_gmf[row][c]) : s_h3[row][c - 64];
      sum += v * Wp[c];
    }
    sum += __shfl_xor(sum, 1);
    sum += __shfl_xor(sum, 2);
    if (q == 0 && p0 + row < total){
      float z = sum + bp[0];
      out[p0 + row] = 1.f / (1.f + __expf(-z));
    }
  }
}

extern "C" void kernel_launch(void* const* d_in, const int* in_sizes, int n_in,
                              void* d_out, int out_size, void* d_ws, size_t ws_size,
                              hipStream_t stream)
{
  const int*   user   = (const int*)  d_in[0];
  const int*   item   = (const int*)  d_in[1];
  const float* Wu_gmf = (const float*)d_in[3];
  const float* bu_gmf = (const float*)d_in[4];
  const float* Wu_mlp = (const float*)d_in[5];
  const float* bu_mlp = (const float*)d_in[6];
  const float* Wi_gmf = (const float*)d_in[7];
  const float* bi_gmf = (const float*)d_in[8];
  const float* Wi_mlp = (const float*)d_in[9];
  const float* bi_mlp = (const float*)d_in[10];
  const float* W1     = (const float*)d_in[11];
  const float* b1     = (const float*)d_in[12];
  const float* W2     = (const float*)d_in[13];
  const float* b2     = (const float*)d_in[14];
  const float* W3     = (const float*)d_in[15];
  const float* b3     = (const float*)d_in[16];
  const float* Wp     = (const float*)d_in[17];
  const float* bp     = (const float*)d_in[18];

  int B     = in_sizes[0];
  int total = in_sizes[1];          // B * N = 409600
  int N     = total / B;            // 100

  short* W1T = (short*)d_ws;                 // [128][128]
  short* W2T = W1T + 128*128;                // [64][128]
  short* W3T = W2T + 64*128;                 // [32][64]

  ncf_prep<<<104, 256, 0, stream>>>(W1, W2, W3, (short*)d_ws);

  int nblk = (total + 63) / 64;
  ncf_main<<<nblk, 256, 0, stream>>>(user, item,
      Wu_gmf, bu_gmf, Wu_mlp, bu_mlp, Wi_gmf, bi_gmf, Wi_mlp, bi_mlp,
      W1T, b1, W2T, b2, W3T, b3, Wp, bp,
      (float*)d_out, N, total);
}